// Round 8
// baseline (149.550 us; speedup 1.0000x reference)
//
#include <hip/hip_runtime.h>

typedef __attribute__((ext_vector_type(4))) short short4v;
typedef __attribute__((ext_vector_type(8))) short short8v;
typedef __attribute__((ext_vector_type(4))) float float4v;
typedef __attribute__((ext_vector_type(4))) int int4v;

#define GLD_LDS16(gsrc, ldst)                                                             \
    __builtin_amdgcn_global_load_lds(                                                     \
        (const __attribute__((address_space(1))) void*)(gsrc),                            \
        (__attribute__((address_space(3))) void*)(ldst), 16, 0, 0)

__device__ __forceinline__ short f2bf(float f) {
    unsigned u = __builtin_bit_cast(unsigned, f);
    u += 0x7fffu + ((u >> 16) & 1u);
    return (short)(u >> 16);
}

__device__ __forceinline__ unsigned pk2(float a, float b) {
    return (unsigned)(unsigned short)f2bf(a) | ((unsigned)(unsigned short)f2bf(b) << 16);
}

// ---------------- x: fp32 -> bf16 (vectorized) ----------------
__global__ void k_cvt_x(const float* __restrict__ x, short* __restrict__ xb) {
    int i = blockIdx.x * blockDim.x + threadIdx.x;
    float4v v = ((const float4v*)x)[i];
    short4v o;
    o[0] = f2bf(v[0]); o[1] = f2bf(v[1]); o[2] = f2bf(v[2]); o[3] = f2bf(v[3]);
    ((short4v*)xb)[i] = o;
}

// ---------------- W[k][n] fp32 -> Wt[n][k] bf16 (LDS tile transpose) ----------------
__global__ void k_transpose(const float* __restrict__ W0, const float* __restrict__ W1,
                            const float* __restrict__ W2, const float* __restrict__ W3,
                            short* __restrict__ Wt) {
    const float* W = blockIdx.z == 0 ? W0 : blockIdx.z == 1 ? W1 : blockIdx.z == 2 ? W2 : W3;
    short* dst = Wt + (size_t)blockIdx.z * 1024 * 1024;
    __shared__ float tile[32][33];
    int x0 = blockIdx.x * 32, y0 = blockIdx.y * 32;
    int tx = threadIdx.x, ty = threadIdx.y;
#pragma unroll
    for (int j = 0; j < 4; j++) {
        int r = ty + j * 8;
        tile[r][tx] = W[(size_t)(y0 + r) * 1024 + x0 + tx];
    }
    __syncthreads();
#pragma unroll
    for (int j = 0; j < 4; j++) {
        int r = ty + j * 8;
        dst[(size_t)(x0 + r) * 1024 + y0 + tx] = f2bf(tile[tx][r]);
    }
}

// ---------------- bf16 MFMA GEMM v2: 128x128 tile, BK=64, 8 waves, 2-phase dbuf ------
template <int MODE>
__launch_bounds__(512, 4)
__global__ void k_gemm2(const short* __restrict__ A, const short* __restrict__ Bt,
                        short* __restrict__ out0, short* __restrict__ out1,
                        float* __restrict__ outF) {
    __shared__ short As[2][128][64];
    __shared__ short Bs[2][128][64];
    int t = threadIdx.x;
    int l = t & 63, w = t >> 6;
    int wm = w >> 2, wn = w & 3;
    int lr = l & 15, lg = l >> 4;
    int m0 = blockIdx.x * 128, n0 = blockIdx.y * 128;
    const short* Bp = Bt + (MODE == 0 ? ((size_t)blockIdx.z << 20) : 0);

    int srow = l >> 3;
    int sg = (l & 7) ^ srow;
    const short* Ab0 = A + (size_t)(m0 + w * 8 + srow) * 1024 + sg * 8;
    const short* Ab1 = Ab0 + 64 * 1024;
    const short* Bb0 = Bp + (size_t)(n0 + w * 8 + srow) * 1024 + sg * 8;
    const short* Bb1 = Bb0 + 64 * 1024;

    float4v acc[4][2] = {};

#define STAGE(bb, k0)                                   \
    do {                                                \
        GLD_LDS16(Ab0 + (k0), &As[bb][w * 8][0]);       \
        GLD_LDS16(Ab1 + (k0), &As[bb][64 + w * 8][0]);  \
        GLD_LDS16(Bb0 + (k0), &Bs[bb][w * 8][0]);       \
        GLD_LDS16(Bb1 + (k0), &Bs[bb][64 + w * 8][0]);  \
    } while (0)

    STAGE(0, 0);
    __syncthreads();
    int cur = 0;

    for (int kt = 0; kt < 16; kt++) {
        if (kt + 1 < 16) STAGE(cur ^ 1, (kt + 1) * 64);
#pragma unroll
        for (int ks = 0; ks < 2; ks++) {
            short8v af[4], bfv[2];
            int hh = ks * 4 + lg;
            int sw = ((hh ^ (lr & 7)) * 8);
#pragma unroll
            for (int fm = 0; fm < 4; fm++)
                af[fm] = *(const short8v*)&As[cur][wm * 64 + fm * 16 + lr][sw];
#pragma unroll
            for (int fn = 0; fn < 2; fn++)
                bfv[fn] = *(const short8v*)&Bs[cur][wn * 32 + fn * 16 + lr][sw];
            __builtin_amdgcn_s_setprio(1);
#pragma unroll
            for (int fm = 0; fm < 4; fm++)
#pragma unroll
                for (int fn = 0; fn < 2; fn++)
                    acc[fm][fn] = (MODE == 1)
                        ? __builtin_amdgcn_mfma_f32_16x16x32_bf16(bfv[fn], af[fm], acc[fm][fn], 0, 0, 0)
                        : __builtin_amdgcn_mfma_f32_16x16x32_bf16(af[fm], bfv[fn], acc[fm][fn], 0, 0, 0);
            __builtin_amdgcn_s_setprio(0);
        }
        __syncthreads();
        cur ^= 1;
    }
#undef STAGE

    if (MODE == 0) {
        short* out = (blockIdx.z == 0) ? out0 : out1;
        float scale = (blockIdx.z == 0) ? 0.125f * 1.44269504088896f : 1.0f;
#pragma unroll
        for (int fm = 0; fm < 4; fm++)
#pragma unroll
            for (int fn = 0; fn < 2; fn++)
#pragma unroll
                for (int r = 0; r < 4; r++) {
                    int m = m0 + wm * 64 + fm * 16 + lg * 4 + r;
                    int n = n0 + wn * 32 + fn * 16 + lr;
                    float v = acc[fm][fn][r] * scale;
                    int b = m >> 11, s = m & 2047, h = n >> 6, dh = n & 63;
                    out[(((size_t)(b * 16 + h)) * 2048 + s) * 64 + dh] = f2bf(v);
                }
    } else if (MODE == 1) {
#pragma unroll
        for (int fm = 0; fm < 4; fm++)
#pragma unroll
            for (int fn = 0; fn < 2; fn++)
#pragma unroll
                for (int r = 0; r < 4; r++) {
                    int n = n0 + wn * 32 + fn * 16 + lg * 4 + r;
                    int m = m0 + wm * 64 + fm * 16 + lr;
                    int b = m >> 11, s = m & 2047, h = n >> 6, dh = n & 63;
                    out0[(((size_t)(b * 16 + h)) * 64 + dh) * 2048 + s] = f2bf(acc[fm][fn][r]);
                }
    } else {
#pragma unroll
        for (int fm = 0; fm < 4; fm++)
#pragma unroll
            for (int fn = 0; fn < 2; fn++)
#pragma unroll
                for (int r = 0; r < 4; r++) {
                    int m = m0 + wm * 64 + fm * 16 + lg * 4 + r;
                    int n = n0 + wn * 32 + fn * 16 + lr;
                    outF[(size_t)m * 1024 + n] = acc[fm][fn][r];
                }
    }
}

// ---------------- causal flash attention v7: swapped QK^T, lane-local softmax ----
// grid (32 bh, 32 tiles LPT-desc), block = 4 waves x 16 q-rows = 64-row tile,
// ~4 blocks/CU. K in LDS (dbuf, swizzled async DMA); V pinned-asm direct loads.
// Swapped mfma(K,Q): lane owns q-row = lr; softmax state is scalar per lane.
__launch_bounds__(256, 4)
__global__ void k_attn(const short* __restrict__ Qb, const short* __restrict__ Kb,
                       const short* __restrict__ Vtb, short* __restrict__ Ob) {
    __shared__ short K_lds[2][64][64];
    __shared__ int p_lds[4][16][36];     // per-wave P: 16 rows x 32 dwords (+4 pad)
    int t = threadIdx.x;
    int l = t & 63, w = t >> 6;
    int lr = l & 15, lg = l >> 4;
    int bh = blockIdx.x;                 // bh%8 -> XCD affinity
    int tile = 31 - (int)blockIdx.y;     // longest first (LPT)
    int nch = tile + 1;

    const short* Qp = Qb + (size_t)bh * 2048 * 64;
    const short* Kp = Kb + (size_t)bh * 2048 * 64;
    const short* Vp = Vtb + (size_t)bh * 64 * 2048;

    auto stageK = [&](int bb, int kv0) {
#pragma unroll
        for (int i = 0; i < 2; i++) {
            int s = t + i * 256;
            int row = s >> 3, cg = s & 7;
            int cs = (cg ^ (row & 7)) * 8;
            GLD_LDS16(&Kp[(size_t)(kv0 + row) * 64 + cs], (short*)K_lds[bb] + (size_t)s * 8);
        }
    };

    stageK(0, 0);

    int q0 = tile * 64 + w * 16;
    short8v qf0 = *(const short8v*)&Qp[(size_t)(q0 + lr) * 64 + lg * 8];
    short8v qf1 = *(const short8v*)&Qp[(size_t)(q0 + lr) * 64 + 32 + lg * 8];

    int voff[4];
#pragma unroll
    for (int dt = 0; dt < 4; dt++) voff[dt] = (dt * 16 + lr) * 4096 + lg * 16;

    float4v o[4] = {};
    float mr = -3e38f;
    float lsum = 0.f;
    int cur = 0;

    __syncthreads();

    for (int ci = 0; ci < nch; ci++) {
        int kv0 = ci * 64;
        bool last = (ci == nch - 1);

        // ---- V loads: pinned asm (unsinkable), 8 vmcnt events ----
        int4v vf[8];
        const short* vbase = Vp + kv0;
#pragma unroll
        for (int dt = 0; dt < 4; dt++) {
            asm volatile("global_load_dwordx4 %0, %1, %2 offset:0"
                         : "=v"(vf[dt]) : "v"(voff[dt]), "s"(vbase) : "memory");
            asm volatile("global_load_dwordx4 %0, %1, %2 offset:64"
                         : "=v"(vf[4 + dt]) : "v"(voff[dt]), "s"(vbase) : "memory");
        }

        // ---- stage next K chunk (2 vmcnt events) ----
        if (!last) stageK(cur ^ 1, kv0 + 64);

        // ---- QK^T swapped: S^T = mfma(K, Q); lane owns q = lr ----
        const short* Kf = (const short*)K_lds[cur];
        float4v s[4] = {};
        __builtin_amdgcn_s_setprio(1);
#pragma unroll
        for (int t4 = 0; t4 < 4; t4++) {
            int krow = t4 * 16 + lr;
            int sw = (krow & 7);
            short8v kfa = *(const short8v*)&Kf[krow * 64 + ((lg ^ sw) * 8)];
            short8v kfb = *(const short8v*)&Kf[krow * 64 + (((lg ^ 4) ^ sw) * 8)];
            s[t4] = __builtin_amdgcn_mfma_f32_16x16x32_bf16(kfa, qf0, s[t4], 0, 0, 0);
            s[t4] = __builtin_amdgcn_mfma_f32_16x16x32_bf16(kfb, qf1, s[t4], 0, 0, 0);
        }
        __builtin_amdgcn_s_setprio(0);

        // lane (lr,lg) holds S[kv = kv0+16*t4+4*lg+r][q = q0+lr]
        if (last) {
#pragma unroll
            for (int t4 = 0; t4 < 4; t4++)
#pragma unroll
                for (int r = 0; r < 4; r++)
                    if (kv0 + t4 * 16 + 4 * lg + r > q0 + lr) s[t4][r] = -3e38f;
        }

        // ---- lane-local online softmax (defer-max) ----
        float mx = -3e38f;
#pragma unroll
        for (int t4 = 0; t4 < 4; t4++)
#pragma unroll
            for (int r = 0; r < 4; r++) mx = fmaxf(mx, s[t4][r]);

        if (!__all(mx - mr <= 8.f)) {    // rare: first chunk / big jump
            float m_ = fmaxf(mx, __shfl_xor(mx, 16));
            m_ = fmaxf(m_, __shfl_xor(m_, 32));
            float mnew = fmaxf(mr, m_);
            float sc = __builtin_amdgcn_exp2f(mr - mnew);
            mr = mnew;
            lsum *= sc;
#pragma unroll
            for (int r = 0; r < 4; r++) {
                float scq = __shfl(sc, lg * 4 + r);   // scale of q-row lg*4+r
                o[0][r] *= scq; o[1][r] *= scq; o[2][r] *= scq; o[3][r] *= scq;
            }
        }

        // exps + pack + P store (4 x ds_write_b64)
#pragma unroll
        for (int t4 = 0; t4 < 4; t4++) {
            float e0 = __builtin_amdgcn_exp2f(s[t4][0] - mr);
            float e1 = __builtin_amdgcn_exp2f(s[t4][1] - mr);
            float e2 = __builtin_amdgcn_exp2f(s[t4][2] - mr);
            float e3 = __builtin_amdgcn_exp2f(s[t4][3] - mr);
            lsum += (e0 + e1) + (e2 + e3);
            unsigned lo = pk2(e0, e1), hi = pk2(e2, e3);
            *(unsigned long long*)&p_lds[w][lr][8 * t4 + 2 * lg] =
                (unsigned long long)lo | ((unsigned long long)hi << 32);
        }

        short8v pa0 = *(const short8v*)&p_lds[w][lr][4 * lg];
        short8v pa1 = *(const short8v*)&p_lds[w][lr][16 + 4 * lg];

        // ---- V ready (keep K staging in flight) ----
        if (last) asm volatile("s_waitcnt vmcnt(0)" ::: "memory");
        else      asm volatile("s_waitcnt vmcnt(2)" ::: "memory");
        __builtin_amdgcn_sched_barrier(0);

        // ---- PV ----
        __builtin_amdgcn_s_setprio(1);
#pragma unroll
        for (int dt = 0; dt < 4; dt++) {
            o[dt] = __builtin_amdgcn_mfma_f32_16x16x32_bf16(pa0, __builtin_bit_cast(short8v, vf[dt]), o[dt], 0, 0, 0);
            o[dt] = __builtin_amdgcn_mfma_f32_16x16x32_bf16(pa1, __builtin_bit_cast(short8v, vf[4 + dt]), o[dt], 0, 0, 0);
        }
        __builtin_amdgcn_s_setprio(0);

        __syncthreads();   // K dbuf flip: all reads done + staging drained
        cur ^= 1;
    }

    // ---- finalize: row-sum across lg-lanes, fetch per-(lg,r) inverse ----
    float ls = lsum;
    ls += __shfl_xor(ls, 16);
    ls += __shfl_xor(ls, 32);
    float inv = 1.0f / ls;               // valid for q-row lr
    float invq[4];
#pragma unroll
    for (int r = 0; r < 4; r++) invq[r] = __shfl(inv, lg * 4 + r);

    int b = bh >> 4, h = bh & 15;
#pragma unroll
    for (int dt = 0; dt < 4; dt++)
#pragma unroll
        for (int r = 0; r < 4; r++) {
            int q = q0 + lg * 4 + r;
            Ob[((size_t)(b * 2048 + q)) * 1024 + h * 64 + dt * 16 + lr] = f2bf(o[dt][r] * invq[r]);
        }
}

extern "C" void kernel_launch(void* const* d_in, const int* in_sizes, int n_in,
                              void* d_out, int out_size, void* d_ws, size_t ws_size,
                              hipStream_t stream) {
    const float* x  = (const float*)d_in[0];
    const float* Wq = (const float*)d_in[1];
    const float* Wk = (const float*)d_in[2];
    const float* Wv = (const float*)d_in[3];
    const float* Wo = (const float*)d_in[4];
    float* out = (float*)d_out;

    char* ws = (char*)d_ws;
    short* xb  = (short*)(ws);                 // [4096][1024] bf16       8 MB
    short* Wtb = (short*)(ws + 8388608);       // 4 x [1024 n][1024 k]    8 MB
    short* Qb  = (short*)(ws + 16777216);      // [B,H,S,Dh] (pre-scaled) 8 MB
    short* Kb  = (short*)(ws + 25165824);      // [B,H,S,Dh]              8 MB
    short* Vtb = (short*)(ws + 33554432);      // [B,H,Dh,S]              8 MB
    short* Ob  = (short*)(ws + 41943040);      // [B,S,D] bf16            8 MB

    k_cvt_x<<<4096, 256, 0, stream>>>(x, xb);
    k_transpose<<<dim3(32, 32, 4), dim3(32, 8), 0, stream>>>(Wq, Wk, Wv, Wo, Wtb);
    k_gemm2<0><<<dim3(32, 8, 2), 512, 0, stream>>>(xb, Wtb, Qb, Kb, nullptr);
    k_gemm2<1><<<dim3(32, 8), 512, 0, stream>>>(xb, Wtb + 2 * 1048576, Vtb, nullptr, nullptr);
    k_attn<<<dim3(32, 32), 256, 0, stream>>>(Qb, Kb, Vtb, Ob);
    k_gemm2<2><<<dim3(32, 8), 512, 0, stream>>>(Ob, Wtb + 3 * 1048576, nullptr, nullptr, out);
}

// Round 9
// 136.823 us; speedup vs baseline: 1.0930x; 1.0930x over previous
//
#include <hip/hip_runtime.h>

typedef __attribute__((ext_vector_type(4))) short short4v;
typedef __attribute__((ext_vector_type(8))) short short8v;
typedef __attribute__((ext_vector_type(4))) float float4v;
typedef __attribute__((ext_vector_type(4))) int int4v;

#define GLD_LDS16(gsrc, ldst)                                                             \
    __builtin_amdgcn_global_load_lds(                                                     \
        (const __attribute__((address_space(1))) void*)(gsrc),                            \
        (__attribute__((address_space(3))) void*)(ldst), 16, 0, 0)

__device__ __forceinline__ short f2bf(float f) {
    unsigned u = __builtin_bit_cast(unsigned, f);
    u += 0x7fffu + ((u >> 16) & 1u);
    return (short)(u >> 16);
}

// ---------------- x: fp32 -> bf16 (vectorized) ----------------
__global__ void k_cvt_x(const float* __restrict__ x, short* __restrict__ xb) {
    int i = blockIdx.x * blockDim.x + threadIdx.x;
    float4v v = ((const float4v*)x)[i];
    short4v o;
    o[0] = f2bf(v[0]); o[1] = f2bf(v[1]); o[2] = f2bf(v[2]); o[3] = f2bf(v[3]);
    ((short4v*)xb)[i] = o;
}

// ---------------- W[k][n] fp32 -> Wt[n][k] bf16 (LDS tile transpose) ----------------
__global__ void k_transpose(const float* __restrict__ W0, const float* __restrict__ W1,
                            const float* __restrict__ W2, const float* __restrict__ W3,
                            short* __restrict__ Wt) {
    const float* W = blockIdx.z == 0 ? W0 : blockIdx.z == 1 ? W1 : blockIdx.z == 2 ? W2 : W3;
    short* dst = Wt + (size_t)blockIdx.z * 1024 * 1024;
    __shared__ float tile[32][33];
    int x0 = blockIdx.x * 32, y0 = blockIdx.y * 32;
    int tx = threadIdx.x, ty = threadIdx.y;
#pragma unroll
    for (int j = 0; j < 4; j++) {
        int r = ty + j * 8;
        tile[r][tx] = W[(size_t)(y0 + r) * 1024 + x0 + tx];
    }
    __syncthreads();
#pragma unroll
    for (int j = 0; j < 4; j++) {
        int r = ty + j * 8;
        dst[(size_t)(x0 + r) * 1024 + y0 + tx] = f2bf(tile[tx][r]);
    }
}

// ---------------- bf16 MFMA GEMM v2: 128x128 tile, BK=64, 8 waves, 2-phase dbuf ------
template <int MODE>
__launch_bounds__(512, 4)
__global__ void k_gemm2(const short* __restrict__ A, const short* __restrict__ Bt,
                        short* __restrict__ out0, short* __restrict__ out1,
                        float* __restrict__ outF) {
    __shared__ short As[2][128][64];
    __shared__ short Bs[2][128][64];
    int t = threadIdx.x;
    int l = t & 63, w = t >> 6;
    int wm = w >> 2, wn = w & 3;
    int lr = l & 15, lg = l >> 4;
    int m0 = blockIdx.x * 128, n0 = blockIdx.y * 128;
    const short* Bp = Bt + (MODE == 0 ? ((size_t)blockIdx.z << 20) : 0);

    int srow = l >> 3;
    int sg = (l & 7) ^ srow;
    const short* Ab0 = A + (size_t)(m0 + w * 8 + srow) * 1024 + sg * 8;
    const short* Ab1 = Ab0 + 64 * 1024;
    const short* Bb0 = Bp + (size_t)(n0 + w * 8 + srow) * 1024 + sg * 8;
    const short* Bb1 = Bb0 + 64 * 1024;

    float4v acc[4][2] = {};

#define STAGE(bb, k0)                                   \
    do {                                                \
        GLD_LDS16(Ab0 + (k0), &As[bb][w * 8][0]);       \
        GLD_LDS16(Ab1 + (k0), &As[bb][64 + w * 8][0]);  \
        GLD_LDS16(Bb0 + (k0), &Bs[bb][w * 8][0]);       \
        GLD_LDS16(Bb1 + (k0), &Bs[bb][64 + w * 8][0]);  \
    } while (0)

    STAGE(0, 0);
    __syncthreads();
    int cur = 0;

    for (int kt = 0; kt < 16; kt++) {
        if (kt + 1 < 16) STAGE(cur ^ 1, (kt + 1) * 64);
#pragma unroll
        for (int ks = 0; ks < 2; ks++) {
            short8v af[4], bfv[2];
            int hh = ks * 4 + lg;
            int sw = ((hh ^ (lr & 7)) * 8);
#pragma unroll
            for (int fm = 0; fm < 4; fm++)
                af[fm] = *(const short8v*)&As[cur][wm * 64 + fm * 16 + lr][sw];
#pragma unroll
            for (int fn = 0; fn < 2; fn++)
                bfv[fn] = *(const short8v*)&Bs[cur][wn * 32 + fn * 16 + lr][sw];
            __builtin_amdgcn_s_setprio(1);
#pragma unroll
            for (int fm = 0; fm < 4; fm++)
#pragma unroll
                for (int fn = 0; fn < 2; fn++)
                    acc[fm][fn] = (MODE == 1)
                        ? __builtin_amdgcn_mfma_f32_16x16x32_bf16(bfv[fn], af[fm], acc[fm][fn], 0, 0, 0)
                        : __builtin_amdgcn_mfma_f32_16x16x32_bf16(af[fm], bfv[fn], acc[fm][fn], 0, 0, 0);
            __builtin_amdgcn_s_setprio(0);
        }
        __syncthreads();
        cur ^= 1;
    }
#undef STAGE

    if (MODE == 0) {
        short* out = (blockIdx.z == 0) ? out0 : out1;
        float scale = (blockIdx.z == 0) ? 0.125f * 1.44269504088896f : 1.0f;
#pragma unroll
        for (int fm = 0; fm < 4; fm++)
#pragma unroll
            for (int fn = 0; fn < 2; fn++)
#pragma unroll
                for (int r = 0; r < 4; r++) {
                    int m = m0 + wm * 64 + fm * 16 + lg * 4 + r;
                    int n = n0 + wn * 32 + fn * 16 + lr;
                    float v = acc[fm][fn][r] * scale;
                    int b = m >> 11, s = m & 2047, h = n >> 6, dh = n & 63;
                    out[(((size_t)(b * 16 + h)) * 2048 + s) * 64 + dh] = f2bf(v);
                }
    } else if (MODE == 1) {
#pragma unroll
        for (int fm = 0; fm < 4; fm++)
#pragma unroll
            for (int fn = 0; fn < 2; fn++)
#pragma unroll
                for (int r = 0; r < 4; r++) {
                    int n = n0 + wn * 32 + fn * 16 + lg * 4 + r;
                    int m = m0 + wm * 64 + fm * 16 + lr;
                    int b = m >> 11, s = m & 2047, h = n >> 6, dh = n & 63;
                    out0[(((size_t)(b * 16 + h)) * 64 + dh) * 2048 + s] = f2bf(acc[fm][fn][r]);
                }
    } else {
#pragma unroll
        for (int fm = 0; fm < 4; fm++)
#pragma unroll
            for (int fn = 0; fn < 2; fn++)
#pragma unroll
                for (int r = 0; r < 4; r++) {
                    int m = m0 + wm * 64 + fm * 16 + lg * 4 + r;
                    int n = n0 + wn * 32 + fn * 16 + lr;
                    outF[(size_t)m * 1024 + n] = acc[fm][fn][r];
                }
    }
}

// ---------------- causal flash attention v8 ----------------
// v4 skeleton + 32 q-rows/wave (2 sub-tiles share each K/V LDS fragment read).
// grid (16,32): block = 4 waves x 32 rows = 128-row tile-pair (15-p, p) = 34 chunks.
// K,V dbuf in swizzled LDS via async DMA; P in XOR-swizzled 64-short rows.
__launch_bounds__(256, 2)
__global__ void k_attn(const short* __restrict__ Qb, const short* __restrict__ Kb,
                       const short* __restrict__ Vtb, short* __restrict__ Ob) {
    __shared__ short K_lds[2][64][64];
    __shared__ short V_lds[2][64][64];
    __shared__ short p_lds[4][2][16][64];
    int t = threadIdx.x;
    int l = t & 63, w = t >> 6;
    int lr = l & 15, lg = l >> 4;

    int L = blockIdx.y * 16 + blockIdx.x;
    int bh = (L & 7) * 4 + ((L >> 3) & 3);   // XCD affinity: 4 heads per XCD
    int p = L >> 5;                          // pair index 0..15

    const short* Qp = Qb + (size_t)bh * 2048 * 64;
    const short* Kp = Kb + (size_t)bh * 2048 * 64;
    const short* Vp = Vtb + (size_t)bh * 64 * 2048;

    int n0 = 32 - 2 * p;                     // chunks for tile hi = 15-p
    int n1 = 2 * p + 2;                      // chunks for tile lo = p
    const int total = 34;

    auto stage = [&](int bb, int kv0) {
#pragma unroll
        for (int i = 0; i < 2; i++) {
            int s = t + i * 256;
            int row = s >> 3, cg = s & 7;
            int cs = (cg ^ (row & 7)) * 8;
            GLD_LDS16(&Kp[(size_t)(kv0 + row) * 64 + cs], (short*)K_lds[bb] + (size_t)s * 8);
            GLD_LDS16(&Vp[(size_t)row * 2048 + kv0 + cs], (short*)V_lds[bb] + (size_t)s * 8);
        }
    };

    stage(0, 0);

    int tile = 15 - p;
    int q0a = tile * 128 + w * 32;
    int q0b = q0a + 16;
    short8v qf0a = *(const short8v*)&Qp[(size_t)(q0a + lr) * 64 + lg * 8];
    short8v qf1a = *(const short8v*)&Qp[(size_t)(q0a + lr) * 64 + 32 + lg * 8];
    short8v qf0b = *(const short8v*)&Qp[(size_t)(q0b + lr) * 64 + lg * 8];
    short8v qf1b = *(const short8v*)&Qp[(size_t)(q0b + lr) * 64 + 32 + lg * 8];

    float4v oa[4] = {}, ob[4] = {};
    float mra[4] = {-3e38f, -3e38f, -3e38f, -3e38f};
    float mrb[4] = {-3e38f, -3e38f, -3e38f, -3e38f};
    float lsa[4] = {0.f, 0.f, 0.f, 0.f};
    float lsb[4] = {0.f, 0.f, 0.f, 0.f};
    int cur = 0;
    int b = bh >> 4, h = bh & 15;

    // softmax + swizzled-P store for one sub-tile (X = 0/1)
    auto softmax_store = [&](float4v (&s)[4], float (&mr)[4], float (&ls)[4],
                             float4v (&o)[4], int X) {
        float mx[4];
#pragma unroll
        for (int r = 0; r < 4; r++)
            mx[r] = fmaxf(fmaxf(s[0][r], s[1][r]), fmaxf(s[2][r], s[3][r]));
        float worst = fmaxf(fmaxf(mx[0] - mr[0], mx[1] - mr[1]),
                            fmaxf(mx[2] - mr[2], mx[3] - mr[3]));
        if (!__all(worst <= 8.f)) {      // rare: first chunk of a tile / big jump
#pragma unroll
            for (int r = 0; r < 4; r++) {
                float m_ = mx[r];
                m_ = fmaxf(m_, __shfl_xor(m_, 1));
                m_ = fmaxf(m_, __shfl_xor(m_, 2));
                m_ = fmaxf(m_, __shfl_xor(m_, 4));
                m_ = fmaxf(m_, __shfl_xor(m_, 8));
                float mnew = fmaxf(mr[r], m_);
                float sc = __builtin_amdgcn_exp2f(mr[r] - mnew);
                mr[r] = mnew;
                ls[r] *= sc;
                o[0][r] *= sc; o[1][r] *= sc; o[2][r] *= sc; o[3][r] *= sc;
            }
        }
        int bg = lr >> 3, co = lr & 7;
#pragma unroll
        for (int r = 0; r < 4; r++) {
            int row = 4 * lg + r, rx = row & 7;
            float e0 = __builtin_amdgcn_exp2f(s[0][r] - mr[r]);
            float e1 = __builtin_amdgcn_exp2f(s[1][r] - mr[r]);
            float e2 = __builtin_amdgcn_exp2f(s[2][r] - mr[r]);
            float e3 = __builtin_amdgcn_exp2f(s[3][r] - mr[r]);
            ls[r] += (e0 + e1) + (e2 + e3);
            p_lds[w][X][row][((bg    ) ^ rx) * 8 + co] = f2bf(e0);
            p_lds[w][X][row][((bg + 2) ^ rx) * 8 + co] = f2bf(e1);
            p_lds[w][X][row][((bg + 4) ^ rx) * 8 + co] = f2bf(e2);
            p_lds[w][X][row][((bg + 6) ^ rx) * 8 + co] = f2bf(e3);
        }
    };

    auto finalize = [&](float4v (&o)[4], float (&ls)[4], int q0) {
        float inv[4];
#pragma unroll
        for (int r = 0; r < 4; r++) {
            float v = ls[r];
            v += __shfl_xor(v, 1);
            v += __shfl_xor(v, 2);
            v += __shfl_xor(v, 4);
            v += __shfl_xor(v, 8);
            inv[r] = 1.0f / v;
        }
#pragma unroll
        for (int dt = 0; dt < 4; dt++)
#pragma unroll
            for (int r = 0; r < 4; r++) {
                int q = q0 + lg * 4 + r;
                Ob[((size_t)(b * 2048 + q)) * 1024 + h * 64 + dt * 16 + lr] = f2bf(o[dt][r] * inv[r]);
            }
    };

    __syncthreads();   // prologue stage drained

    for (int ci = 0; ci < total; ci++) {
        bool second = ci >= n0;
        int ntile = second ? n1 : n0;
        int c = second ? ci - n0 : ci;
        int kv0 = c * 64;

        int cin = ci + 1;
        if (cin < total) {
            int kvn = (cin < n0) ? cin * 64 : (cin - n0) * 64;
            stage(cur ^ 1, kvn);
        }

        // ---- QK^T for both sub-tiles; K fragments read once ----
        const short* Kf = (const short*)K_lds[cur];
        float4v sa[4] = {}, sb[4] = {};
        __builtin_amdgcn_s_setprio(1);
#pragma unroll
        for (int t4 = 0; t4 < 4; t4++) {
            int krow = t4 * 16 + lr;
            int sw = (krow & 7);
            short8v kfa = *(const short8v*)&Kf[krow * 64 + ((lg ^ sw) * 8)];
            short8v kfb = *(const short8v*)&Kf[krow * 64 + (((lg ^ 4) ^ sw) * 8)];
            sa[t4] = __builtin_amdgcn_mfma_f32_16x16x32_bf16(qf0a, kfa, sa[t4], 0, 0, 0);
            sa[t4] = __builtin_amdgcn_mfma_f32_16x16x32_bf16(qf1a, kfb, sa[t4], 0, 0, 0);
            sb[t4] = __builtin_amdgcn_mfma_f32_16x16x32_bf16(qf0b, kfa, sb[t4], 0, 0, 0);
            sb[t4] = __builtin_amdgcn_mfma_f32_16x16x32_bf16(qf1b, kfb, sb[t4], 0, 0, 0);
        }
        __builtin_amdgcn_s_setprio(0);

        // ---- causal mask (per sub-tile gate; covers boundary + fully-masked) ----
        if (kv0 + 63 > q0a) {
#pragma unroll
            for (int t4 = 0; t4 < 4; t4++)
#pragma unroll
                for (int r = 0; r < 4; r++)
                    if (kv0 + t4 * 16 + lr > q0a + lg * 4 + r) sa[t4][r] = -3e38f;
        }
        if (kv0 + 63 > q0b) {
#pragma unroll
            for (int t4 = 0; t4 < 4; t4++)
#pragma unroll
                for (int r = 0; r < 4; r++)
                    if (kv0 + t4 * 16 + lr > q0b + lg * 4 + r) sb[t4][r] = -3e38f;
        }

        // ---- softmax + P store, both sub-tiles ----
        softmax_store(sa, mra, lsa, oa, 0);
        softmax_store(sb, mrb, lsb, ob, 1);

        // ---- P fragment reads (conflict-free swizzled) ----
        int prx = lr & 7;
        short8v pa0 = *(const short8v*)&p_lds[w][0][lr][8 * (lg ^ prx)];
        short8v pa1 = *(const short8v*)&p_lds[w][0][lr][8 * ((4 + lg) ^ prx)];
        short8v pb0 = *(const short8v*)&p_lds[w][1][lr][8 * (lg ^ prx)];
        short8v pb1 = *(const short8v*)&p_lds[w][1][lr][8 * ((4 + lg) ^ prx)];

        // ---- PV: V fragments read once, feed both sub-tiles ----
        const short* Vf = (const short*)V_lds[cur];
        __builtin_amdgcn_s_setprio(1);
#pragma unroll
        for (int dt = 0; dt < 4; dt++) {
            int vrow = dt * 16 + lr;
            int sw = (vrow & 7);
            short8v vfa = *(const short8v*)&Vf[vrow * 64 + ((lg ^ sw) * 8)];
            short8v vfb = *(const short8v*)&Vf[vrow * 64 + (((lg ^ 4) ^ sw) * 8)];
            oa[dt] = __builtin_amdgcn_mfma_f32_16x16x32_bf16(pa0, vfa, oa[dt], 0, 0, 0);
            oa[dt] = __builtin_amdgcn_mfma_f32_16x16x32_bf16(pa1, vfb, oa[dt], 0, 0, 0);
            ob[dt] = __builtin_amdgcn_mfma_f32_16x16x32_bf16(pb0, vfa, ob[dt], 0, 0, 0);
            ob[dt] = __builtin_amdgcn_mfma_f32_16x16x32_bf16(pb1, vfb, ob[dt], 0, 0, 0);
        }
        __builtin_amdgcn_s_setprio(0);

        // ---- tile finalize / switch ----
        if (c == ntile - 1) {
            finalize(oa, lsa, q0a);
            finalize(ob, lsb, q0b);
            if (!second) {
                tile = p;
                q0a = tile * 128 + w * 32;
                q0b = q0a + 16;
                qf0a = *(const short8v*)&Qp[(size_t)(q0a + lr) * 64 + lg * 8];
                qf1a = *(const short8v*)&Qp[(size_t)(q0a + lr) * 64 + 32 + lg * 8];
                qf0b = *(const short8v*)&Qp[(size_t)(q0b + lr) * 64 + lg * 8];
                qf1b = *(const short8v*)&Qp[(size_t)(q0b + lr) * 64 + 32 + lg * 8];
#pragma unroll
                for (int dt = 0; dt < 4; dt++) {
                    oa[dt] = float4v{0.f, 0.f, 0.f, 0.f};
                    ob[dt] = float4v{0.f, 0.f, 0.f, 0.f};
                }
#pragma unroll
                for (int r = 0; r < 4; r++) {
                    mra[r] = -3e38f; mrb[r] = -3e38f;
                    lsa[r] = 0.f; lsb[r] = 0.f;
                }
            }
        }

        __syncthreads();   // buffer flip: all reads of cur done + staging drained
        cur ^= 1;
    }
}

extern "C" void kernel_launch(void* const* d_in, const int* in_sizes, int n_in,
                              void* d_out, int out_size, void* d_ws, size_t ws_size,
                              hipStream_t stream) {
    const float* x  = (const float*)d_in[0];
    const float* Wq = (const float*)d_in[1];
    const float* Wk = (const float*)d_in[2];
    const float* Wv = (const float*)d_in[3];
    const float* Wo = (const float*)d_in[4];
    float* out = (float*)d_out;

    char* ws = (char*)d_ws;
    short* xb  = (short*)(ws);                 // [4096][1024] bf16       8 MB
    short* Wtb = (short*)(ws + 8388608);       // 4 x [1024 n][1024 k]    8 MB
    short* Qb  = (short*)(ws + 16777216);      // [B,H,S,Dh] (pre-scaled) 8 MB
    short* Kb  = (short*)(ws + 25165824);      // [B,H,S,Dh]              8 MB
    short* Vtb = (short*)(ws + 33554432);      // [B,H,Dh,S]              8 MB
    short* Ob  = (short*)(ws + 41943040);      // [B,S,D] bf16            8 MB

    k_cvt_x<<<4096, 256, 0, stream>>>(x, xb);
    k_transpose<<<dim3(32, 32, 4), dim3(32, 8), 0, stream>>>(Wq, Wk, Wv, Wo, Wtb);
    k_gemm2<0><<<dim3(32, 8, 2), 512, 0, stream>>>(xb, Wtb, Qb, Kb, nullptr);
    k_gemm2<1><<<dim3(32, 8), 512, 0, stream>>>(xb, Wtb + 2 * 1048576, Vtb, nullptr, nullptr);
    k_attn<<<dim3(16, 32), 256, 0, stream>>>(Qb, Kb, Vtb, Ob);
    k_gemm2<2><<<dim3(32, 8), 512, 0, stream>>>(Ob, Wtb + 3 * 1048576, nullptr, nullptr, out);
}